// Round 1
// baseline (809.795 us; speedup 1.0000x reference)
//
#include <hip/hip_runtime.h>

typedef unsigned short u16;
typedef __attribute__((ext_vector_type(8))) short short8;
typedef __attribute__((ext_vector_type(4))) short short4v;
typedef __attribute__((ext_vector_type(8))) __bf16 bf16x8;
typedef __attribute__((ext_vector_type(4))) float f32x4;

#define SEQ 2048
#define DM 1024
#define NH 16
#define HD 64

__device__ __forceinline__ u16 f2bf(float f) {
    unsigned u = __float_as_uint(f);
    u += 0x7fffu + ((u >> 16) & 1u);
    return (u16)(u >> 16);
}

__device__ __forceinline__ f32x4 mfma16(short8 a, short8 b, f32x4 c) {
    return __builtin_amdgcn_mfma_f32_16x16x32_bf16(
        __builtin_bit_cast(bf16x8, a), __builtin_bit_cast(bf16x8, b), c, 0, 0, 0);
}

__device__ __forceinline__ void gll16(const u16* g, u16* l) {
    __builtin_amdgcn_global_load_lds(
        (__attribute__((address_space(1))) void*)(void*)g,
        (__attribute__((address_space(3))) void*)(void*)l, 16, 0, 0);
}

// ---------------- convert Q f32 -> bf16 (row-major [4096][1024]) ----------------
__global__ void cvt_q(const float* __restrict__ in, u16* __restrict__ outp) {
    const int i = blockIdx.x * 256 + threadIdx.x;
    const float4 v = ((const float4*)in)[i];
    short4v r;
    r.x = (short)f2bf(v.x); r.y = (short)f2bf(v.y);
    r.z = (short)f2bf(v.z); r.w = (short)f2bf(v.w);
    ((short4v*)outp)[i] = r;
}

// -------- transpose-convert W [K=1024][N=1024] f32 -> Wt [N][K] bf16 ------------
__global__ void wtrans(const float* __restrict__ w0, const float* __restrict__ w1,
                       const float* __restrict__ w2, const float* __restrict__ w3,
                       u16* __restrict__ o0, u16* __restrict__ o1,
                       u16* __restrict__ o2, u16* __restrict__ o3) {
    const float* w = blockIdx.z == 0 ? w0 : blockIdx.z == 1 ? w1 : blockIdx.z == 2 ? w2 : w3;
    u16* o = blockIdx.z == 0 ? o0 : blockIdx.z == 1 ? o1 : blockIdx.z == 2 ? o2 : o3;
    __shared__ float t[64][65];
    const int tid = threadIdx.x;
    const int r0 = blockIdx.y * 64, c0 = blockIdx.x * 64;
#pragma unroll
    for (int p = 0; p < 4; ++p) {
        const int r = (tid >> 4) + p * 16;
        const int c = (tid & 15) * 4;
        const float4 v = *(const float4*)(w + (size_t)(r0 + r) * DM + c0 + c);
        t[r][c] = v.x; t[r][c + 1] = v.y; t[r][c + 2] = v.z; t[r][c + 3] = v.w;
    }
    __syncthreads();
    const int c = tid >> 2, rr0 = (tid & 3) * 16;
    short8 s0, s1;
#pragma unroll
    for (int j = 0; j < 8; ++j) s0[j] = (short)f2bf(t[rr0 + j][c]);
#pragma unroll
    for (int j = 0; j < 8; ++j) s1[j] = (short)f2bf(t[rr0 + 8 + j][c]);
    u16* dst = o + (size_t)(c0 + c) * DM + r0 + rr0;
    *(short8*)dst = s0;
    *(short8*)(dst + 8) = s1;
}

// ---------------- 128x128 bf16 MFMA GEMM, K=1024 --------------------------------
// MODE 0: z in {0,1,2} selects (B,bias,out); scatter bf16 to [b*NH+h][s][d]; z==0 applies *scale.
// MODE 1: f32 row-major output.
template <int MODE>
__global__ __launch_bounds__(256) void gemm128(
    const u16* __restrict__ A,
    const u16* __restrict__ B0, const u16* __restrict__ B1, const u16* __restrict__ B2,
    const float* __restrict__ bias0, const float* __restrict__ bias1, const float* __restrict__ bias2,
    u16* __restrict__ O0, u16* __restrict__ O1, u16* __restrict__ O2,
    float* __restrict__ Of, const float* __restrict__ scaleptr) {
    __shared__ __align__(16) u16 As[2][128 * 32];
    __shared__ __align__(16) u16 Bs[2][128 * 32];
    const int tid = threadIdx.x;
    const int lane = tid & 63, wid = tid >> 6;
    const int wr = wid >> 1, wc = wid & 1;
    const int row0 = blockIdx.y * 128, col0 = blockIdx.x * 128;

    const u16* Bt; const float* bias; u16* Osc = nullptr; float mult = 1.0f;
    if (MODE == 0) {
        const int z = blockIdx.z;
        Bt   = (z == 0) ? B0 : (z == 1) ? B1 : B2;
        bias = (z == 0) ? bias0 : (z == 1) ? bias1 : bias2;
        Osc  = (z == 0) ? O0 : (z == 1) ? O1 : O2;
        if (z == 0) mult = *scaleptr;
    } else {
        Bt = B0; bias = bias0;
    }

    f32x4 acc[4][4];
#pragma unroll
    for (int m = 0; m < 4; ++m)
#pragma unroll
        for (int n = 0; n < 4; ++n) acc[m][n] = (f32x4){0.f, 0.f, 0.f, 0.f};

    auto stage = [&](int buf, int t) {
        const int k0 = t * 32;
#pragma unroll
        for (int i = 0; i < 2; ++i) {
            const int ci = i * 256 + tid;
            const int r = ci >> 2, p = ci & 3;
            const int sl = p ^ ((r >> 1) & 3);  // XOR swizzle (T2): spread 64B rows across bank quads
            gll16(A  + (size_t)(row0 + r) * DM + k0 + sl * 8, &As[buf][ci * 8]);
            gll16(Bt + (size_t)(col0 + r) * DM + k0 + sl * 8, &Bs[buf][ci * 8]);
        }
    };

    stage(0, 0);
    const int kb = lane >> 4, lr = lane & 15;
    for (int t = 0; t < 32; ++t) {
        const int cur = t & 1;
        __syncthreads();                       // drains vmcnt -> buf[cur] staged; prev reads done
        if (t + 1 < 32) stage(cur ^ 1, t + 1); // prefetch next tile into other buffer
        short8 a[4], b[4];
#pragma unroll
        for (int m = 0; m < 4; ++m) {
            const int r = wr * 64 + m * 16 + lr;
            const int sl = kb ^ ((r >> 1) & 3);
            a[m] = *(const short8*)&As[cur][r * 32 + sl * 8];
        }
#pragma unroll
        for (int n = 0; n < 4; ++n) {
            const int r = wc * 64 + n * 16 + lr;
            const int sl = kb ^ ((r >> 1) & 3);
            b[n] = *(const short8*)&Bs[cur][r * 32 + sl * 8];
        }
#pragma unroll
        for (int m = 0; m < 4; ++m)
#pragma unroll
            for (int n = 0; n < 4; ++n) acc[m][n] = mfma16(a[m], b[n], acc[m][n]);
    }

    const int g = lane >> 4;
#pragma unroll
    for (int n = 0; n < 4; ++n) {
        const int col = col0 + wc * 64 + n * 16 + lr;
        const float bv = bias[col];
#pragma unroll
        for (int m = 0; m < 4; ++m) {
#pragma unroll
            for (int reg = 0; reg < 4; ++reg) {
                const int row = row0 + wr * 64 + m * 16 + g * 4 + reg;
                const float v = (acc[m][n][reg] + bv) * mult;
                if (MODE == 0) {
                    const int bi = row >> 11, s = row & 2047;
                    const int h = col >> 6, d = col & 63;
                    Osc[(((size_t)(bi * NH + h)) * SEQ + s) * HD + d] = f2bf(v);
                } else {
                    Of[(size_t)row * DM + col] = v;
                }
            }
        }
    }
}

// ---------------- attention: per (bh, 64-row q-tile), two-pass softmax ----------
__global__ __launch_bounds__(256) void attn_kernel(
    const u16* __restrict__ qbuf, const u16* __restrict__ kbuf, const u16* __restrict__ vbuf,
    float* __restrict__ attnw, u16* __restrict__ ao) {
    __shared__ __align__(16) u16 Qs[64 * 64];    // [qrow][d]  swizzled (8 slots/row)
    __shared__ __align__(16) u16 Ks[128 * 64];   // [key][d]   swizzled (8 slots/row)
    __shared__ __align__(16) u16 Vt[64 * 128];   // [d][k]     swizzled (16 slots/row)
    __shared__ __align__(16) u16 Ps[64 * 128];   // [q][k]     swizzled (16 slots/row)

    const int tid = threadIdx.x, lane = tid & 63, w = tid >> 6;
    const int bh = blockIdx.y, qt = blockIdx.x;
    const u16* qg = qbuf + ((size_t)bh * SEQ + qt * 64) * HD;
    const u16* kg = kbuf + (size_t)bh * SEQ * HD;
    const u16* vg = vbuf + (size_t)bh * SEQ * HD;

    // stage Q once (8KB)
#pragma unroll
    for (int i = 0; i < 2; ++i) {
        const int ci = i * 256 + tid;
        const int r = ci >> 3, p = ci & 7, sl = p ^ (r & 7);
        gll16(qg + r * HD + sl * 8, &Qs[ci * 8]);
    }

    const int kb = lane >> 4, lr = lane & 15, g = kb;
    float M[4], L[4];
#pragma unroll
    for (int i = 0; i < 4; ++i) { M[i] = -1e30f; L[i] = 0.f; }

    // ---- pass 1: running max + sum ----
    for (int kt = 0; kt < 16; ++kt) {
        __syncthreads();
#pragma unroll
        for (int i = 0; i < 4; ++i) {
            const int ci = i * 256 + tid;
            const int r = ci >> 3, p = ci & 7, sl = p ^ (r & 7);
            gll16(kg + (size_t)(kt * 128 + r) * HD + sl * 8, &Ks[ci * 8]);
        }
        __syncthreads();
        f32x4 s[8];
#pragma unroll
        for (int n = 0; n < 8; ++n) s[n] = (f32x4){0.f, 0.f, 0.f, 0.f};
#pragma unroll
        for (int ks = 0; ks < 2; ++ks) {
            const int qr = w * 16 + lr;
            const int sl = (ks * 4 + kb) ^ (qr & 7);
            short8 aq = *(const short8*)&Qs[qr * HD + sl * 8];
#pragma unroll
            for (int n = 0; n < 8; ++n) {
                const int kr = n * 16 + lr;
                const int sl2 = (ks * 4 + kb) ^ (kr & 7);
                short8 bk8 = *(const short8*)&Ks[kr * HD + sl2 * 8];
                s[n] = mfma16(aq, bk8, s[n]);
            }
        }
#pragma unroll
        for (int reg = 0; reg < 4; ++reg) {
            float mx = s[0][reg];
#pragma unroll
            for (int n = 1; n < 8; ++n) mx = fmaxf(mx, s[n][reg]);
            mx = fmaxf(mx, __shfl_xor(mx, 1));
            mx = fmaxf(mx, __shfl_xor(mx, 2));
            mx = fmaxf(mx, __shfl_xor(mx, 4));
            mx = fmaxf(mx, __shfl_xor(mx, 8));
            const float nm = fmaxf(M[reg], mx);
            float rs = 0.f;
#pragma unroll
            for (int n = 0; n < 8; ++n) rs += __expf(s[n][reg] - nm);
            rs += __shfl_xor(rs, 1); rs += __shfl_xor(rs, 2);
            rs += __shfl_xor(rs, 4); rs += __shfl_xor(rs, 8);
            L[reg] = L[reg] * __expf(M[reg] - nm) + rs;
            M[reg] = nm;
        }
    }
    float Li[4];
#pragma unroll
    for (int reg = 0; reg < 4; ++reg) Li[reg] = 1.f / L[reg];

    f32x4 o[4];
#pragma unroll
    for (int vn = 0; vn < 4; ++vn) o[vn] = (f32x4){0.f, 0.f, 0.f, 0.f};

    // ---- pass 2: exact weights, store f32, PV accumulate ----
    for (int kt = 0; kt < 16; ++kt) {
        __syncthreads();
#pragma unroll
        for (int i = 0; i < 4; ++i) {
            const int ci = i * 256 + tid;
            const int r = ci >> 3, p = ci & 7, sl = p ^ (r & 7);
            gll16(kg + (size_t)(kt * 128 + r) * HD + sl * 8, &Ks[ci * 8]);
        }
        // V transpose-stage via regs: [k][d] -> Vt[d][k] (swizzled)
#pragma unroll
        for (int i = 0; i < 4; ++i) {
            const int kk = i * 32 + (tid >> 3);
            const int d0 = (tid & 7) * 8;
            short8 vv = *(const short8*)(vg + (size_t)(kt * 128 + kk) * HD + d0);
#pragma unroll
            for (int j = 0; j < 8; ++j) {
                const int d = d0 + j;
                const int sl = (kk >> 3) ^ (d & 7);
                Vt[d * 128 + sl * 8 + (kk & 7)] = (u16)vv[j];
            }
        }
        __syncthreads();
        f32x4 s[8];
#pragma unroll
        for (int n = 0; n < 8; ++n) s[n] = (f32x4){0.f, 0.f, 0.f, 0.f};
#pragma unroll
        for (int ks = 0; ks < 2; ++ks) {
            const int qr = w * 16 + lr;
            const int sl = (ks * 4 + kb) ^ (qr & 7);
            short8 aq = *(const short8*)&Qs[qr * HD + sl * 8];
#pragma unroll
            for (int n = 0; n < 8; ++n) {
                const int kr = n * 16 + lr;
                const int sl2 = (ks * 4 + kb) ^ (kr & 7);
                short8 bk8 = *(const short8*)&Ks[kr * HD + sl2 * 8];
                s[n] = mfma16(aq, bk8, s[n]);
            }
        }
        // weights: store f32 to output, bf16 to Ps (wave-local rows)
#pragma unroll
        for (int reg = 0; reg < 4; ++reg) {
            const int qr = qt * 64 + w * 16 + g * 4 + reg;
            float* wrow = attnw + ((size_t)bh * SEQ + qr) * SEQ + kt * 128;
            const int prow = w * 16 + g * 4 + reg;
#pragma unroll
            for (int n = 0; n < 8; ++n) {
                const float wv = __expf(s[n][reg] - M[reg]) * Li[reg];
                wrow[n * 16 + lr] = wv;
                const int k = n * 16 + lr;
                const int sl = (k >> 3) ^ (prow & 7);
                Ps[prow * 128 + sl * 8 + (k & 7)] = f2bf(wv);
            }
        }
        // PV: O += P @ V  (Ps rows are wave-local; in-wave LDS ordering suffices)
#pragma unroll
        for (int ks = 0; ks < 4; ++ks) {
            const int pr = w * 16 + lr;
            const int sl = (ks * 4 + kb) ^ (pr & 7);
            short8 pa = *(const short8*)&Ps[pr * 128 + sl * 8];
#pragma unroll
            for (int vn = 0; vn < 4; ++vn) {
                const int d = vn * 16 + lr;
                const int sl2 = (ks * 4 + kb) ^ (d & 7);
                short8 vb8 = *(const short8*)&Vt[d * 128 + sl2 * 8];
                o[vn] = mfma16(pa, vb8, o[vn]);
            }
        }
    }

    // epilogue: attnout bf16 [4096][1024], col = h*64+d
    const int b = bh >> 4, h = bh & 15;
#pragma unroll
    for (int vn = 0; vn < 4; ++vn) {
#pragma unroll
        for (int reg = 0; reg < 4; ++reg) {
            const int srow = qt * 64 + w * 16 + g * 4 + reg;
            const int d = vn * 16 + lr;
            ao[((size_t)(b * SEQ + srow)) * DM + h * HD + d] = f2bf(o[vn][reg]);
        }
    }
}

// --------------------------------- launcher -------------------------------------
extern "C" void kernel_launch(void* const* d_in, const int* in_sizes, int n_in,
                              void* d_out, int out_size, void* d_ws, size_t ws_size,
                              hipStream_t stream) {
    const float* Q     = (const float*)d_in[0];
    const float* Wq    = (const float*)d_in[1];
    const float* bq    = (const float*)d_in[2];
    const float* Wk    = (const float*)d_in[3];
    const float* bk    = (const float*)d_in[4];
    const float* Wv    = (const float*)d_in[5];
    const float* bv    = (const float*)d_in[6];
    const float* Wo    = (const float*)d_in[7];
    const float* bo    = (const float*)d_in[8];
    const float* scale = (const float*)d_in[9];

    float* out   = (float*)d_out;                       // [4096][1024] f32
    float* attnw = out + (size_t)4096 * 1024;           // [32][2048][2048] f32

    char* ws = (char*)d_ws;
    u16* Qb  = (u16*)(ws);                              // [4096][1024] bf16
    u16* WqT = (u16*)(ws + (8u << 20));                 // [1024][1024] bf16 each
    u16* WkT = WqT + (1u << 20);
    u16* WvT = WkT + (1u << 20);
    u16* WoT = WvT + (1u << 20);
    u16* qbh = (u16*)(ws + (16u << 20));                // [32][2048][64] bf16
    u16* kbh = qbh + (size_t)32 * SEQ * HD;
    u16* vbh = kbh + (size_t)32 * SEQ * HD;
    u16* ao  = (u16*)(ws + (40u << 20));                // [4096][1024] bf16

    cvt_q<<<dim3(4096), dim3(256), 0, stream>>>(Q, Qb);
    wtrans<<<dim3(16, 16, 4), dim3(256), 0, stream>>>(Wq, Wk, Wv, Wo, WqT, WkT, WvT, WoT);
    gemm128<0><<<dim3(8, 32, 3), dim3(256), 0, stream>>>(
        Qb, WqT, WkT, WvT, bq, bk, bv, qbh, kbh, vbh, nullptr, scale);
    attn_kernel<<<dim3(32, 32), dim3(256), 0, stream>>>(qbh, kbh, vbh, attnw, ao);
    gemm128<1><<<dim3(8, 32, 1), dim3(256), 0, stream>>>(
        ao, WoT, nullptr, nullptr, bo, nullptr, nullptr, nullptr, nullptr, nullptr, out, scale);
}